// Round 4
// baseline (1180.465 us; speedup 1.0000x reference)
//
#include <hip/hip_runtime.h>

typedef __attribute__((ext_vector_type(4))) float f4v;
typedef __attribute__((ext_vector_type(8))) short s8v;

#define YPITCH 72   // shorts; 144 B row pitch -> 8 disjoint 4-bank classes on b128 reads
#define NB 8        // batches per block
#define MROWS 136   // 8 x 17 rows
#define MT 9        // padded to 144 rows

static __device__ __forceinline__ short f2bf(float f) {
    unsigned u = __builtin_bit_cast(unsigned, f);
    unsigned r = (u + 0x7FFFu + ((u >> 16) & 1u)) >> 16;  // RNE
    return (short)r;
}

// W[3][256][256] (k,f,o) fp32  ->  Wt[3][256][256] (k,o,f) bf16, via LDS tile transpose
__global__ void wt_transpose_kernel(const float* __restrict__ W, short* __restrict__ Wt) {
    __shared__ short t[64][65];
    int k  = blockIdx.x >> 4;
    int r  = blockIdx.x & 15;
    int f0 = (r >> 2) << 6;
    int o0 = (r & 3) << 6;
    const float* Wk  = W  + k * 65536;
    short*       Wtk = Wt + k * 65536;
    #pragma unroll
    for (int e = 0; e < 16; e++) {
        int idx = e * 256 + threadIdx.x;
        int f = idx >> 6, o = idx & 63;
        t[f][o] = f2bf(Wk[(f0 + f) * 256 + o0 + o]);
    }
    __syncthreads();
    #pragma unroll
    for (int e = 0; e < 16; e++) {
        int idx = e * 256 + threadIdx.x;
        int o = idx >> 6, f = idx & 63;
        Wtk[(o0 + o) * 256 + f0 + f] = t[f][o];
    }
}

// One adjacency-row dot product; i and K compile-time constants after unroll.
template<int K>
static __device__ __forceinline__ float row_sum(const float* __restrict__ adj,
                                                const float xq[17], int i) {
    float a;
    if (K == 0) {
        a = adj[i * 17 + i] * xq[i];
    } else if (K == 1) {
        a = 0.f;
        #pragma unroll
        for (int j = i + 1; j < 17; j++) a += adj[i * 17 + j] * xq[j];
    } else {
        a = 0.f;
        #pragma unroll
        for (int j = 0; j < i; j++) a += adj[i * 17 + j] * xq[j];
    }
    return a;
}

template<int K>
static __device__ __forceinline__ void agg_store(const float* __restrict__ adj,
                                                 const float xq[17], short* yb) {
    // row pairs: compute -> cvt_pk -> store immediately (y transient, low VGPR)
    #pragma unroll
    for (int t = 0; t < 8; t++) {
        float a0 = row_sum<K>(adj, xq, 2 * t);
        float a1 = row_sum<K>(adj, xq, 2 * t + 1);
        unsigned r;
        asm("v_cvt_pk_bf16_f32 %0, %1, %2" : "=v"(r) : "v"(a0), "v"(a1));
        yb[(2 * t) * YPITCH]     = (short)(r & 0xffffu);
        yb[(2 * t + 1) * YPITCH] = (short)(r >> 16);
    }
    float a = row_sum<K>(adj, xq, 16);
    unsigned r;
    asm("v_cvt_pk_bf16_f32 %0, %1, %2" : "=v"(r) : "v"(a), "v"(a));
    yb[16 * YPITCH] = (short)(r & 0xffffu);
}

// 8-wave block, NB=8 batches: wave w aggregates batch w, owns N-slice [w*32,w*32+32).
// x loads software-pipelined one fc-chunk ahead (T14: issue early, consume 3 k-steps
// later under agg+MFMA). W fragments direct from L2. Ys double-buffered, ONE lgkm-only
// barrier per k-step. Swapped MFMA operands -> contiguous float4 epilogue stores.
__global__ __launch_bounds__(512, 4) void gconv_kernel(
        const float* __restrict__ x, const short* __restrict__ Wt,
        const float* __restrict__ adj, const float* __restrict__ bias,
        float* __restrict__ out) {
    __shared__ __align__(16) short Ys[2][144 * YPITCH];   // 2 x 20736 B = 41472 B

    const int tid  = threadIdx.x;
    const int wave = tid >> 6;       // 0..7
    const int lane = tid & 63;
    const int mn   = lane & 15;
    const int quad = lane >> 4;
    const int bb   = wave;           // batch for aggregation
    const int f    = lane;           // f-column within 64-wide chunk

    const float* xg = x   + (size_t)blockIdx.x * (NB * 17 * 256);
    float*       og = out + (size_t)blockIdx.x * (NB * 17 * 256);

    // zero pad rows 136..143 of both buffers (one-time; covered by first barrier)
    for (int idx = tid; idx < 8 * YPITCH; idx += 512) {
        Ys[0][MROWS * YPITCH + idx] = 0;
        Ys[1][MROWS * YPITCH + idx] = 0;
    }

    f4v acc[MT][2];
    #pragma unroll
    for (int nt = 0; nt < 2; nt++) {
        f4v bv = *(const f4v*)(bias + wave * 32 + nt * 16 + quad * 4);
        #pragma unroll
        for (int mt = 0; mt < MT; mt++) acc[mt][nt] = bv;
    }

    // prime chunk 0
    float xq[17];
    #pragma unroll
    for (int j = 0; j < 17; j++) xq[j] = xg[(bb * 17 + j) * 256 + f];

    int buf = 0;
    #pragma unroll
    for (int c = 0; c < 4; c++) {
        const int fc0 = c * 64;

        // ---- issue NEXT chunk's x loads now; consumed after 3 k-steps (~2000 cy) ----
        float xn[17];
        if (c < 3) {
            #pragma unroll
            for (int j = 0; j < 17; j++)
                xn[j] = xg[(bb * 17 + j) * 256 + fc0 + 64 + f];
        }

        #pragma unroll
        for (int k = 0; k < 3; k++) {
            // ---- W fragments: global->reg from L2, issued before agg (latency cover) ----
            const short* Wtk = Wt + k * 65536;
            s8v wf[2][2];
            #pragma unroll
            for (int ks = 0; ks < 2; ks++)
                #pragma unroll
                for (int nt = 0; nt < 2; nt++)
                    wf[ks][nt] = *(const s8v*)(Wtk + (wave * 32 + nt * 16 + mn) * 256
                                               + fc0 + ks * 32 + quad * 8);

            // ---- aggregation: batch bb, all 17 joints, fused cvt+store ----
            short* yb = &Ys[buf][(bb * 17) * YPITCH + f];
            if      (k == 0) agg_store<0>(adj, xq, yb);
            else if (k == 1) agg_store<1>(adj, xq, yb);
            else             agg_store<2>(adj, xq, yb);

            // ---- one barrier per k-step: drain LDS writes only (no vmcnt drain) ----
            asm volatile("s_waitcnt lgkmcnt(0)" ::: "memory");
            __builtin_amdgcn_s_barrier();
            __builtin_amdgcn_sched_barrier(0);

            // ---- MFMA: A = W rows (o), B = Y rows -> D rows are contiguous o ----
            #pragma unroll
            for (int ks = 0; ks < 2; ks++) {
                const int ko = ks * 32 + quad * 8;
                #pragma unroll
                for (int mt = 0; mt < MT; mt++) {
                    s8v af = *(const s8v*)(&Ys[buf][(mt * 16 + mn) * YPITCH + ko]);
                    acc[mt][0] = __builtin_amdgcn_mfma_f32_16x16x32_bf16(
                        wf[ks][0], af, acc[mt][0], 0, 0, 0);
                    acc[mt][1] = __builtin_amdgcn_mfma_f32_16x16x32_bf16(
                        wf[ks][1], af, acc[mt][1], 0, 0, 0);
                }
            }
            buf ^= 1;
        }

        // rotate ping-pong (renamed away by the full unroll)
        if (c < 3) {
            #pragma unroll
            for (int j = 0; j < 17; j++) xq[j] = xn[j];
        }
    }

    // ---- epilogue: D row = quad*4+rg = o (contiguous) -> one float4 store per tile ----
    #pragma unroll
    for (int mt = 0; mt < MT; mt++) {
        const int r = mt * 16 + mn;
        if (r < MROWS) {
            #pragma unroll
            for (int nt = 0; nt < 2; nt++)
                *(f4v*)(og + r * 256 + wave * 32 + nt * 16 + quad * 4) = acc[mt][nt];
        }
    }
}

extern "C" void kernel_launch(void* const* d_in, const int* in_sizes, int n_in,
                              void* d_out, int out_size, void* d_ws, size_t ws_size,
                              hipStream_t stream) {
    const float* x    = (const float*)d_in[0];
    const float* W    = (const float*)d_in[1];
    const float* adj  = (const float*)d_in[2];
    const float* bias = (const float*)d_in[3];
    float* out = (float*)d_out;
    short* Wt  = (short*)d_ws;  // 3*256*256 bf16 = 393 KB

    hipLaunchKernelGGL(wt_transpose_kernel, dim3(48), dim3(256), 0, stream, W, Wt);
    hipLaunchKernelGGL(gconv_kernel, dim3(16384 / NB), dim3(512), 0, stream,
                       x, Wt, adj, bias, out);
}

// Round 5
// 783.593 us; speedup vs baseline: 1.5065x; 1.5065x over previous
//
#include <hip/hip_runtime.h>

typedef __attribute__((ext_vector_type(4))) float f4v;
typedef __attribute__((ext_vector_type(8))) short s8v;

#define YPITCH 72               // shorts; 144 B row pitch -> uniform 8-slot bank walk
#define NB 8                    // batches per block
#define MROWS 136               // 8 x 17 rows
#define MT 9                    // padded to 144 rows
#define RSTRIDE (144 * YPITCH)  // shorts per k-region

static __device__ __forceinline__ short f2bf(float f) {
    unsigned u = __builtin_bit_cast(unsigned, f);
    unsigned r = (u + 0x7FFFu + ((u >> 16) & 1u)) >> 16;  // RNE
    return (short)r;
}

// W[3][256][256] (k,f,o) fp32  ->  Wt[3][256][256] (k,o,f) bf16, via LDS tile transpose
__global__ void wt_transpose_kernel(const float* __restrict__ W, short* __restrict__ Wt) {
    __shared__ short t[64][65];
    int k  = blockIdx.x >> 4;
    int r  = blockIdx.x & 15;
    int f0 = (r >> 2) << 6;
    int o0 = (r & 3) << 6;
    const float* Wk  = W  + k * 65536;
    short*       Wtk = Wt + k * 65536;
    #pragma unroll
    for (int e = 0; e < 16; e++) {
        int idx = e * 256 + threadIdx.x;
        int f = idx >> 6, o = idx & 63;
        t[f][o] = f2bf(Wk[(f0 + f) * 256 + o0 + o]);
    }
    __syncthreads();
    #pragma unroll
    for (int e = 0; e < 16; e++) {
        int idx = e * 256 + threadIdx.x;
        int o = idx >> 6, f = idx & 63;
        Wtk[(o0 + o) * 256 + f0 + f] = t[f][o];
    }
}

// One adjacency-row dot product; i and K compile-time constants after unroll.
template<int K>
static __device__ __forceinline__ float row_sum(const float* __restrict__ adj,
                                                const float xq[17], int i) {
    float a;
    if (K == 0) {
        a = adj[i * 17 + i] * xq[i];
    } else if (K == 1) {
        a = 0.f;
        #pragma unroll
        for (int j = i + 1; j < 17; j++) a += adj[i * 17 + j] * xq[j];
    } else {
        a = 0.f;
        #pragma unroll
        for (int j = 0; j < i; j++) a += adj[i * 17 + j] * xq[j];
    }
    return a;
}

template<int K>
static __device__ __forceinline__ void agg_store(const float* __restrict__ adj,
                                                 const float xq[17], short* yb) {
    // row pairs: compute -> cvt_pk -> store immediately (y transient, low VGPR)
    #pragma unroll
    for (int t = 0; t < 8; t++) {
        float a0 = row_sum<K>(adj, xq, 2 * t);
        float a1 = row_sum<K>(adj, xq, 2 * t + 1);
        unsigned r;
        asm("v_cvt_pk_bf16_f32 %0, %1, %2" : "=v"(r) : "v"(a0), "v"(a1));
        yb[(2 * t) * YPITCH]     = (short)(r & 0xffffu);
        yb[(2 * t + 1) * YPITCH] = (short)(r >> 16);
    }
    float a = row_sum<K>(adj, xq, 16);
    unsigned r;
    asm("v_cvt_pk_bf16_f32 %0, %1, %2" : "=v"(r) : "v"(a), "v"(a));
    yb[16 * YPITCH] = (short)(r & 0xffffu);
}

// Two-phase chunk: [agg k=0,1,2 into 3 regions | issue next x into xq | lgkm barrier]
// then [108 MFMAs with W(k+1) frags issued behind k's MFMAs | barrier].
// Explicitly called 4x from the kernel (no big-loop unroll pragma -> no SROA hazard).
template<int PREFETCH>
static __device__ __forceinline__ void chunk_body(
        const int fc0, const float* __restrict__ xg, const short* __restrict__ Wt,
        const float* __restrict__ adj, short* __restrict__ Ys,
        float xq[17], f4v acc[MT][2],
        const int wave, const int mn, const int quad, const int f, const int bb) {
    // ---- W fragments for k=0: issued first, hidden under the whole agg phase ----
    s8v wf[2][2];
    #pragma unroll
    for (int ks = 0; ks < 2; ks++)
        #pragma unroll
        for (int nt = 0; nt < 2; nt++)
            wf[ks][nt] = *(const s8v*)(Wt + (wave * 32 + nt * 16 + mn) * 256
                                       + fc0 + ks * 32 + quad * 8);

    // ---- phase 1: aggregate all three adjacency parts into 3 LDS regions ----
    short* yb = Ys + (bb * 17) * YPITCH + f;
    agg_store<0>(adj, xq, yb);
    agg_store<1>(adj, xq, yb + RSTRIDE);
    agg_store<2>(adj, xq, yb + 2 * RSTRIDE);

    // ---- next chunk's x: last read of xq was agg k=2, so overwrite in place ----
    // (vmcnt loads; NOT drained by the lgkm barrier; consumed next chunk => hidden
    //  under barrier + 108 MFMAs)
    if (PREFETCH) {
        #pragma unroll
        for (int j = 0; j < 17; j++)
            xq[j] = xg[(bb * 17 + j) * 256 + fc0 + 64 + f];
    }

    asm volatile("s_waitcnt lgkmcnt(0)" ::: "memory");
    __builtin_amdgcn_s_barrier();
    __builtin_amdgcn_sched_barrier(0);

    // ---- phase 2: dense MFMA over k=0..2 (A = W rows, B = Y rows) ----
    #pragma unroll
    for (int k = 0; k < 3; k++) {
        const short* Yk = Ys + k * RSTRIDE;
        #pragma unroll
        for (int ks = 0; ks < 2; ks++) {
            const int ko = ks * 32 + quad * 8;
            #pragma unroll
            for (int mt = 0; mt < MT; mt++) {
                s8v af = *(const s8v*)(Yk + (mt * 16 + mn) * YPITCH + ko);
                acc[mt][0] = __builtin_amdgcn_mfma_f32_16x16x32_bf16(
                    wf[ks][0], af, acc[mt][0], 0, 0, 0);
                acc[mt][1] = __builtin_amdgcn_mfma_f32_16x16x32_bf16(
                    wf[ks][1], af, acc[mt][1], 0, 0, 0);
            }
        }
        // W fragments for k+1: issued behind k's MFMAs (WAR-safe in-order reuse)
        if (k < 2) {
            const short* Wn = Wt + (k + 1) * 65536;
            #pragma unroll
            for (int ks = 0; ks < 2; ks++)
                #pragma unroll
                for (int nt = 0; nt < 2; nt++)
                    wf[ks][nt] = *(const s8v*)(Wn + (wave * 32 + nt * 16 + mn) * 256
                                               + fc0 + ks * 32 + quad * 8);
        }
    }
    __builtin_amdgcn_s_barrier();  // regions reused by next chunk's agg
}

// 8-wave block, NB=8 batches: wave w aggregates batch w, owns N-slice [w*32,w*32+32).
// Pad rows 136..143 are never written: their garbage lands only in D columns
// (n = pad Y-rows) that the epilogue never stores -> no zero-init needed.
__global__ __launch_bounds__(512, 4) void gconv_kernel(
        const float* __restrict__ x, const short* __restrict__ Wt,
        const float* __restrict__ adj, const float* __restrict__ bias,
        float* __restrict__ out) {
    __shared__ __align__(16) short Ys[3 * RSTRIDE];   // 62208 B (2 blocks/CU)

    const int tid  = threadIdx.x;
    const int wave = tid >> 6;       // 0..7
    const int lane = tid & 63;
    const int mn   = lane & 15;
    const int quad = lane >> 4;
    const int bb   = wave;           // batch for aggregation
    const int f    = lane;           // f-column within 64-wide chunk

    const float* xg = x   + (size_t)blockIdx.x * (NB * 17 * 256);
    float*       og = out + (size_t)blockIdx.x * (NB * 17 * 256);

    f4v acc[MT][2];
    #pragma unroll
    for (int nt = 0; nt < 2; nt++) {
        f4v bv = *(const f4v*)(bias + wave * 32 + nt * 16 + quad * 4);
        #pragma unroll
        for (int mt = 0; mt < MT; mt++) acc[mt][nt] = bv;
    }

    // prime chunk 0
    float xq[17];
    #pragma unroll
    for (int j = 0; j < 17; j++) xq[j] = xg[(bb * 17 + j) * 256 + f];

    chunk_body<1>(  0, xg, Wt, adj, Ys, xq, acc, wave, mn, quad, f, bb);
    chunk_body<1>( 64, xg, Wt, adj, Ys, xq, acc, wave, mn, quad, f, bb);
    chunk_body<1>(128, xg, Wt, adj, Ys, xq, acc, wave, mn, quad, f, bb);
    chunk_body<0>(192, xg, Wt, adj, Ys, xq, acc, wave, mn, quad, f, bb);

    // ---- epilogue: D row = quad*4+rg = o (contiguous) -> one float4 store per tile ----
    #pragma unroll
    for (int mt = 0; mt < MT; mt++) {
        const int r = mt * 16 + mn;
        if (r < MROWS) {
            #pragma unroll
            for (int nt = 0; nt < 2; nt++)
                *(f4v*)(og + r * 256 + wave * 32 + nt * 16 + quad * 4) = acc[mt][nt];
        }
    }
}

extern "C" void kernel_launch(void* const* d_in, const int* in_sizes, int n_in,
                              void* d_out, int out_size, void* d_ws, size_t ws_size,
                              hipStream_t stream) {
    const float* x    = (const float*)d_in[0];
    const float* W    = (const float*)d_in[1];
    const float* adj  = (const float*)d_in[2];
    const float* bias = (const float*)d_in[3];
    float* out = (float*)d_out;
    short* Wt  = (short*)d_ws;  // 3*256*256 bf16 = 393 KB

    hipLaunchKernelGGL(wt_transpose_kernel, dim3(48), dim3(256), 0, stream, W, Wt);
    hipLaunchKernelGGL(gconv_kernel, dim3(16384 / NB), dim3(512), 0, stream,
                       x, Wt, adj, bias, out);
}

// Round 6
// 751.742 us; speedup vs baseline: 1.5703x; 1.0424x over previous
//
#include <hip/hip_runtime.h>

typedef __attribute__((ext_vector_type(4))) float f4v;
typedef __attribute__((ext_vector_type(8))) short s8v;

#define YPITCH 72   // shorts; 144 B row pitch
#define NB 4        // batches per block
#define MROWS 68    // 4 x 17 rows
#define MT 5        // padded to 80 rows

static __device__ __forceinline__ short f2bf(float f) {
    unsigned u = __builtin_bit_cast(unsigned, f);
    unsigned r = (u + 0x7FFFu + ((u >> 16) & 1u)) >> 16;  // RNE
    return (short)r;
}

// W[3][256][256] (k,f,o) fp32  ->  Wt[3][256][256] (k,o,f) bf16, via LDS tile transpose
__global__ void wt_transpose_kernel(const float* __restrict__ W, short* __restrict__ Wt) {
    __shared__ short t[64][65];
    int k  = blockIdx.x >> 4;
    int r  = blockIdx.x & 15;
    int f0 = (r >> 2) << 6;
    int o0 = (r & 3) << 6;
    const float* Wk  = W  + k * 65536;
    short*       Wtk = Wt + k * 65536;
    #pragma unroll
    for (int e = 0; e < 16; e++) {
        int idx = e * 256 + threadIdx.x;
        int f = idx >> 6, o = idx & 63;
        t[f][o] = f2bf(Wk[(f0 + f) * 256 + o0 + o]);
    }
    __syncthreads();
    #pragma unroll
    for (int e = 0; e < 16; e++) {
        int idx = e * 256 + threadIdx.x;
        int o = idx >> 6, f = idx & 63;
        Wtk[(o0 + o) * 256 + f0 + f] = t[f][o];
    }
}

// One adjacency-row dot product; i and K compile-time constants after unroll.
// (read-only array param -- proven SROA-clean in R3)
template<int K>
static __device__ __forceinline__ float row_sum(const float* __restrict__ adj,
                                                const float xq[17], int i) {
    float a;
    if (K == 0) {
        a = adj[i * 17 + i] * xq[i];
    } else if (K == 1) {
        a = 0.f;
        #pragma unroll
        for (int j = i + 1; j < 17; j++) a += adj[i * 17 + j] * xq[j];
    } else {
        a = 0.f;
        #pragma unroll
        for (int j = 0; j < i; j++) a += adj[i * 17 + j] * xq[j];
    }
    return a;
}

template<int K>
static __device__ __forceinline__ void agg_store(const float* __restrict__ adj,
                                                 const float xq[17], short* yb) {
    #pragma unroll
    for (int t = 0; t < 8; t++) {
        float a0 = row_sum<K>(adj, xq, 2 * t);
        float a1 = row_sum<K>(adj, xq, 2 * t + 1);
        unsigned r;
        asm("v_cvt_pk_bf16_f32 %0, %1, %2" : "=v"(r) : "v"(a0), "v"(a1));
        yb[(2 * t) * YPITCH]     = (short)(r & 0xffffu);
        yb[(2 * t + 1) * YPITCH] = (short)(r >> 16);
    }
    float a = row_sum<K>(adj, xq, 16);
    unsigned r;
    asm("v_cvt_pk_bf16_f32 %0, %1, %2" : "=v"(r) : "v"(a), "v"(a));
    yb[16 * YPITCH] = (short)(r & 0xffffu);
}

// One fc-chunk, expanded inline as a macro (NO function boundary: xa/xb stay SROA-able).
// XC = current x registers (consumed by agg); XN = next chunk's (prefetched if PF).
#define CHUNK(FC0, XC, XN, PF)                                                        \
    do {                                                                              \
        if (PF) {                                                                     \
            _Pragma("unroll")                                                         \
            for (int j = 0; j < 17; j++)                                              \
                XN[j] = xg[(bb * 17 + j) * 256 + (FC0) + 64 + f];                     \
        }                                                                             \
        _Pragma("unroll")                                                             \
        for (int k = 0; k < 3; k++) {                                                 \
            const short* Wtk = Wt + k * 65536;                                        \
            s8v wf[2][4];                                                             \
            _Pragma("unroll")                                                         \
            for (int ks = 0; ks < 2; ks++)                                            \
                _Pragma("unroll")                                                     \
                for (int nt = 0; nt < 4; nt++)                                        \
                    wf[ks][nt] = *(const s8v*)(Wtk                                    \
                        + (wave * 64 + nt * 16 + mn) * 256                            \
                        + (FC0) + ks * 32 + quad * 8);                                \
            short* yb = &Ys[buf][(bb * 17) * YPITCH + f];                             \
            if      (k == 0) agg_store<0>(adj, XC, yb);                               \
            else if (k == 1) agg_store<1>(adj, XC, yb);                               \
            else             agg_store<2>(adj, XC, yb);                               \
            asm volatile("s_waitcnt lgkmcnt(0)" ::: "memory");                        \
            __builtin_amdgcn_s_barrier();                                             \
            __builtin_amdgcn_sched_barrier(0);                                        \
            __builtin_amdgcn_s_setprio(1);                                            \
            _Pragma("unroll")                                                         \
            for (int ks = 0; ks < 2; ks++) {                                          \
                const int ko = ks * 32 + quad * 8;                                    \
                _Pragma("unroll")                                                     \
                for (int mt = 0; mt < MT; mt++) {                                     \
                    s8v af = *(const s8v*)(&Ys[buf][(mt * 16 + mn) * YPITCH + ko]);   \
                    _Pragma("unroll")                                                 \
                    for (int nt = 0; nt < 4; nt++)                                    \
                        acc[mt][nt] = __builtin_amdgcn_mfma_f32_16x16x32_bf16(        \
                            wf[ks][nt], af, acc[mt][nt], 0, 0, 0);                    \
                }                                                                     \
            }                                                                         \
            __builtin_amdgcn_s_setprio(0);                                            \
            buf ^= 1;                                                                 \
        }                                                                             \
    } while (0)

// 4-wave block, NB=4: wave w aggregates batch w, owns N-slice [w*64, w*64+64).
// af fragments shared across nt=4 -> 44% fewer LDS b128 reads than 8-wave/nt=2.
// 3 blocks/CU (reg-capped) -> three independently-phased barrier groups overlap
// agg(VALU) with MFMA; setprio biases the matrix-pipe wave.
__global__ __launch_bounds__(256, 3) void gconv_kernel(
        const float* __restrict__ x, const short* __restrict__ Wt,
        const float* __restrict__ adj, const float* __restrict__ bias,
        float* __restrict__ out) {
    __shared__ __align__(16) short Ys[2][80 * YPITCH];   // 2 x 11520 B = 23040 B

    const int tid  = threadIdx.x;
    const int wave = tid >> 6;       // 0..3
    const int lane = tid & 63;
    const int mn   = lane & 15;
    const int quad = lane >> 4;
    const int bb   = wave;           // batch for aggregation
    const int f    = lane;           // f-column within 64-wide chunk

    const float* xg = x   + (size_t)blockIdx.x * (NB * 17 * 256);
    float*       og = out + (size_t)blockIdx.x * (NB * 17 * 256);

    f4v acc[MT][4];
    #pragma unroll
    for (int nt = 0; nt < 4; nt++) {
        f4v bv = *(const f4v*)(bias + wave * 64 + nt * 16 + quad * 4);
        #pragma unroll
        for (int mt = 0; mt < MT; mt++) acc[mt][nt] = bv;
    }

    // prime chunk 0
    float xa[17], xb[17];
    #pragma unroll
    for (int j = 0; j < 17; j++) xa[j] = xg[(bb * 17 + j) * 256 + f];

    int buf = 0;
    CHUNK(0,   xa, xb, 1);
    CHUNK(64,  xb, xa, 1);
    CHUNK(128, xa, xb, 1);
    CHUNK(192, xb, xa, 0);

    // ---- epilogue: D row = quad*4+rg = o (contiguous) -> one float4 store per tile ----
    #pragma unroll
    for (int mt = 0; mt < MT; mt++) {
        const int r = mt * 16 + mn;
        if (r < MROWS) {
            #pragma unroll
            for (int nt = 0; nt < 4; nt++)
                *(f4v*)(og + r * 256 + wave * 64 + nt * 16 + quad * 4) = acc[mt][nt];
        }
    }
}

extern "C" void kernel_launch(void* const* d_in, const int* in_sizes, int n_in,
                              void* d_out, int out_size, void* d_ws, size_t ws_size,
                              hipStream_t stream) {
    const float* x    = (const float*)d_in[0];
    const float* W    = (const float*)d_in[1];
    const float* adj  = (const float*)d_in[2];
    const float* bias = (const float*)d_in[3];
    float* out = (float*)d_out;
    short* Wt  = (short*)d_ws;  // 3*256*256 bf16 = 393 KB

    hipLaunchKernelGGL(wt_transpose_kernel, dim3(48), dim3(256), 0, stream, W, Wt);
    hipLaunchKernelGGL(gconv_kernel, dim3(16384 / NB), dim3(256), 0, stream,
                       x, Wt, adj, bias, out);
}